// Round 4
// baseline (333.613 us; speedup 1.0000x reference)
//
#include <hip/hip_runtime.h>

#define N_IMG 2048
#define SRC   64
#define TH    128
#define TW    128
// Padded LDS image: source cols/rows -2..65 stored at 0..67 (2-wide zero ring).
// clamp(x0, -2, 64) then +2 => all four bilinear corners read in-bounds, and
// every invalid/pad corner reads a structural zero. No per-corner masks.
#define LW    68
#define LN    (LW * LW)   // 4624 floats = 18496 B per image

typedef float v2f __attribute__((ext_vector_type(2)));

__global__ __launch_bounds__(256) void affine_sample_kernel(
    const float* __restrict__ affine,
    const float* __restrict__ fill,
    const float* __restrict__ stroke,
    float* __restrict__ out)
{
    __shared__ float sF[LN];
    __shared__ float sS[LN];
    __shared__ float th[6];

    const int n   = blockIdx.x;
    const int tid = threadIdx.x;

    // --- Theta: computed once per block (6 lanes), broadcast via LDS.
    if (tid < 6) {
        const float t = affine[n * 6 + tid];
        float v;
        if (tid < 2)      v = 2.0f / (1.0f + __expf(-t));
        else if (tid < 4) v = 2.0f * tanhf(t);
        else              v = tanhf(t);
        th[tid] = v;
    }

    // --- Zero the 2-wide border ring (disjoint from interior).
    // rows 0,1,66,67 full width: 2*68 = 136 pairs
    for (int i = tid; i < 136; i += 256) {
        const int r = i / LW, c = i % LW;          // r in {0,1}
        sF[r * LW + c] = 0.f;  sF[(67 - r) * LW + c] = 0.f;
        sS[r * LW + c] = 0.f;  sS[(67 - r) * LW + c] = 0.f;
    }
    // cols 0,1,66,67 for rows 2..65: 64*2 = 128 pairs
    for (int i = tid; i < 128; i += 256) {
        const int r = 2 + (i >> 1), c = i & 1;     // c in {0,1}
        sF[r * LW + c] = 0.f;  sF[r * LW + 67 - c] = 0.f;
        sS[r * LW + c] = 0.f;  sS[r * LW + 67 - c] = 0.f;
    }

    // --- Stage interior with float4 global loads (coalesced).
    const float* __restrict__ fptr = fill   + (size_t)n * SRC * SRC;
    const float* __restrict__ sptr = stroke + (size_t)n * SRC * SRC;
    for (int i = tid; i < SRC * SRC / 4; i += 256) {
        const float4 f = reinterpret_cast<const float4*>(fptr)[i];
        const float4 s = reinterpret_cast<const float4*>(sptr)[i];
        const int y  = i >> 4;
        const int x4 = (i & 15) << 2;
        const int d  = (y + 2) * LW + x4 + 2;
        sF[d] = f.x; sF[d + 1] = f.y; sF[d + 2] = f.z; sF[d + 3] = f.w;
        sS[d] = s.x; sS[d + 1] = s.y; sS[d + 2] = s.z; sS[d + 3] = s.w;
    }

    __syncthreads();

    const float a00 = th[0];
    const float a11 = th[1];
    const float a01 = th[2];
    const float a10 = th[3];
    const float a02 = th[4];
    const float a12 = th[5];

    float* __restrict__ outF = out + (size_t)n * TH * TW;
    float* __restrict__ outS = out + (size_t)N_IMG * TH * TW + (size_t)n * TH * TW;

    const int lane = tid & 63;   // full-wave row coverage: x = lane + 64*j
    const int wv   = tid >> 6;   // 4 waves -> 4 consecutive rows per iteration

    // Source coords with PAD folded in:
    //   isx = a00*(px+0.5) + Cx(row);  Cx = 64*(a01*Y + a02 - a00) + 31.5
    for (int it = 0; it < 32; ++it) {
        const int py = it * 4 + wv;
        const float Y  = ((float)py + 0.5f) * (2.0f / TH) - 1.0f;
        const float Cx = 64.0f * (a01 * Y + a02 - a00) + 31.5f;
        const float Cy = 64.0f * (a11 * Y + a12 - a10) + 31.5f;
        float* __restrict__ oF = outF + py * TW + lane;
        float* __restrict__ oS = outS + py * TW + lane;

        #pragma unroll
        for (int j = 0; j < 2; ++j) {
            const float fx  = (float)(lane + 64 * j) + 0.5f;
            const float isx = fmaf(a00, fx, Cx);
            const float isy = fmaf(a10, fx, Cy);

            const float x0f = floorf(isx);
            const float y0f = floorf(isy);
            const float wx  = isx - x0f;
            const float wy  = isy - y0f;

            // clamp into the zero-ringed LDS image; invalid corners read 0
            const int xc = min(max((int)x0f, -2), 64);
            const int yc = min(max((int)y0f, -2), 64);
            const int idx = (yc + 2) * LW + (xc + 2);

            const v2f v00 = { sF[idx],          sS[idx]          };
            const v2f v10 = { sF[idx + 1],      sS[idx + 1]      };
            const v2f v01 = { sF[idx + LW],     sS[idx + LW]     };
            const v2f v11 = { sF[idx + LW + 1], sS[idx + LW + 1] };

            // packed lerp-form bilinear: 3 pk_sub + 3 pk_fma
            const v2f top = v00 + wx * (v10 - v00);
            const v2f bot = v01 + wx * (v11 - v01);
            const v2f r   = top + wy * (bot - top);

            oF[64 * j] = r.x;   // one 256 B contiguous segment per wave-instr
            oS[64 * j] = r.y;
        }
    }
}

extern "C" void kernel_launch(void* const* d_in, const int* in_sizes, int n_in,
                              void* d_out, int out_size, void* d_ws, size_t ws_size,
                              hipStream_t stream) {
    const float* affine = (const float*)d_in[0];  // (N, 6)
    const float* fill   = (const float*)d_in[1];  // (N, 64, 64)
    const float* stroke = (const float*)d_in[2];  // (N, 64, 64)
    // d_in[3] = targetsize, unused by the computation.
    float* out = (float*)d_out;                   // fill_out then stroke_out, each (N,128,128)

    affine_sample_kernel<<<dim3(N_IMG), dim3(256), 0, stream>>>(affine, fill, stroke, out);
}